// Round 4
// baseline (382.779 us; speedup 1.0000x reference)
//
#include <hip/hip_runtime.h>

constexpr int EMB  = 128;   // EMB_DIM
constexpr int H1D  = 256;   // 2*HIDDEN
constexpr int H2D  = 128;   // HIDDEN
constexpr int VOC  = 4096;  // VOCAB
constexpr int NSL  = 32;    // wsum slices (atomic-contention spreading)
constexpr int RPB  = 4;     // emb rows per tile in embW1 GEMM

// LDS-privatized histogram geometry: 64 node-ranges x 4 edge-slice teams.
// Assumes n <= NRANGE*RMAX = 65536 (problem fixes n = 50000).
constexpr int NRANGE = 64;
constexpr int RMAX   = 1024;
constexpr int TEAMS  = 4;

constexpr int GEMM_B  = VOC / RPB;            // 1024
constexpr int HIST_B  = NRANGE * TEAMS;       // 256
constexpr int KB_GRID = GEMM_B + HIST_B;      // 1280 = 5 blocks/CU

// ---------------- kA: zero state; block 0 builds flagbits + count from x_position.
// flagbits/count are zeroed and atomically built inside the SAME block (block 0),
// so there is no cross-block ordering hazard. cnt[] is NOT zeroed here: it is
// fully written by k_alloc (sum of histogram partials) before any reader.
__global__ void kA_init(int* count, unsigned int* flagbits, unsigned int* needw,
                        float* wagg, float* wsum, int* nflag, int* total,
                        const int* __restrict__ xpos,
                        int n, int nwords, int np) {
    int t = threadIdx.x;
    if (blockIdx.x == 0) {
        for (int i = t; i < nwords; i += 256) flagbits[i] = 0u;
        for (int i = t; i < n; i += 256) count[i] = 0;
        __syncthreads();
        for (int i = t; i < np; i += 256) {
            int v = xpos[i];
            atomicAdd(&count[v], 1);
            atomicOr(&flagbits[v >> 5], 1u << (v & 31));
        }
        if (t == 0) { *nflag = 0; *total = 0; }
    } else {
        const int stride = (gridDim.x - 1) * 256;
        const int i0 = (blockIdx.x - 1) * 256 + t;
        for (int i = i0; i < n; i += stride) wagg[i] = 0.0f;
        for (int i = i0; i < nwords; i += stride) needw[i] = 0u;
        for (int i = i0; i < NSL * H1D; i += stride) wsum[i] = 0.0f;
    }
}

// ---------------- kB: blocks [0,1024) embW1 = emb @ W1 (one 4-row tile each)
//   || blocks [1024,1280): LDS-privatized in-degree histogram + needed-row marks.
// Hist block h: range = h & 63 (owns nodes [range*R, range*R+R)), team = h/64
// (owns a quarter of the edge list). Counts go to LDS (no global atomics), then
// plain coalesced stores into cntp[team]. Flag-mark (2% of edges) executes in
// the unique block owning the edge's col range -> exactly once per edge.
__global__ __launch_bounds__(256) void kB_embW1_hist(
        const float* __restrict__ emb, const float* __restrict__ W1,
        float* __restrict__ embW1,
        const int* __restrict__ row, const int* __restrict__ col,
        const unsigned int* __restrict__ flagbits,
        int* __restrict__ cntp, unsigned int* markw, int ne, int R) {
    int t = threadIdx.x;
    if (blockIdx.x < GEMM_B) {
        __shared__ float er[RPB][EMB];   // 2 KB
        int r0 = blockIdx.x * RPB;
        for (int i = t; i < RPB * EMB; i += 256)
            er[i / EMB][i % EMB] = emb[(size_t)r0 * EMB + i];
        __syncthreads();
        float acc[RPB];
#pragma unroll
        for (int rr = 0; rr < RPB; rr++) acc[rr] = 0.0f;
        for (int k = 0; k < EMB; k++) {
            float w = W1[k * H1D + t];
#pragma unroll
            for (int rr = 0; rr < RPB; rr++) acc[rr] += er[rr][k] * w;
        }
#pragma unroll
        for (int rr = 0; rr < RPB; rr++)
            embW1[(size_t)(r0 + rr) * H1D + t] = acc[rr];
    } else {
        __shared__ int lc[RMAX];         // 4 KB
        int h     = blockIdx.x - GEMM_B;
        int range = h & (NRANGE - 1);
        int team  = h / NRANGE;
        int base  = range * R;
        for (int i = t; i < R; i += 256) lc[i] = 0;
        __syncthreads();
        int q  = (((ne + TEAMS - 1) / TEAMS) + 255) & ~255;   // 256-aligned slice
        int e1 = min(ne, team * q + q);
        for (int e = team * q + t; e < e1; e += 256) {
            int c = col[e];
            unsigned int d = (unsigned int)(c - base);
            if (d < (unsigned int)R) {
                atomicAdd(&lc[d], 1);                          // LDS atomic
                if ((flagbits[c >> 5] >> (c & 31)) & 1u) {     // ~2% of edges
                    int r = row[e];
                    atomicOr(&markw[r >> 5], 1u << (r & 31));
                }
            }
        }
        __syncthreads();
        int s = NRANGE * R;              // team stride
        for (int i = t; i < R; i += 256) cntp[team * s + base + i] = lc[i];
    }
}

// ------- k_alloc: cv = sum of 4 histogram partials (written to cnt[] for fconv);
//         need = mark||flag; canonical needbits via wave-ballot plain store;
//         CSR bump-alloc (wave-aggregated atomics); wagg self term;
//         packed pk[v] = {x[v], rsqrt(cnt[v]+1)} so scatter does 1 gather not 2.
__global__ void k_alloc(unsigned int* needw,
                        const unsigned int* __restrict__ flagbits,
                        const int* __restrict__ cntp, const int* __restrict__ count,
                        const int* __restrict__ x,
                        float* wagg, int* needlist, int* nflag, int* total,
                        int* offs, int* cursor, int2* pk, int* cnt,
                        int n, int sTeam) {
    int v = blockIdx.x * blockDim.x + threadIdx.x;
    int lane = threadIdx.x & 63;
    int cv = 0;
    bool need = false;
    if (v < n) {
        cv = cntp[v] + cntp[sTeam + v] + cntp[2 * sTeam + v] + cntp[3 * sTeam + v];
        cnt[v] = cv;
        float dv = rsqrtf((float)cv + 1.0f);
        int2 p; p.x = x[v]; p.y = __float_as_int(dv);
        pk[v] = p;
        bool mark = (needw[v >> 5] >> (v & 31)) & 1u;
        bool flag = (flagbits[v >> 5] >> (v & 31)) & 1u;
        need = mark || flag;
        if (flag) wagg[v] = (float)count[v] / ((float)cv + 1.0f);  // count*dinv^2
    }
    // canonical needbits: ballot -> one word per half-wave, plain store by owner lane
    unsigned long long nm = __ballot(need);
    int wbase = (v & ~63) >> 5;            // v is wave-aligned at lane 0
    if (lane == 0)  needw[wbase]     = (unsigned int)(nm & 0xffffffffu);
    if (lane == 32) needw[wbase + 1] = (unsigned int)(nm >> 32);
    int seg = need ? cv : 0;
    int incl = seg;
#pragma unroll
    for (int d = 1; d < 64; d <<= 1) {
        int t2 = __shfl_up(incl, d);
        if (lane >= d) incl += t2;
    }
    int excl = incl - seg;
    int wave_total = __shfl(incl, 63);
    int rank = __popcll(nm & ((1ull << lane) - 1));
    int wcnt = __popcll(nm);
    int base_id = 0, base_off = 0;
    if (lane == 0) {
        if (wcnt > 0)       base_id  = atomicAdd(nflag, wcnt);
        if (wave_total > 0) base_off = atomicAdd(total, wave_total);
    }
    base_id  = __shfl(base_id, 0);
    base_off = __shfl(base_off, 0);
    if (need) {
        needlist[base_id + rank] = v;
        int o = base_off + excl;
        offs[v] = o;
        cursor[v] = o;
    }
}

// ---------------- k_scatter: filtered to needed cols via L1-resident bitmask;
//   srowp[pos] = pk[row] (single 8B gather); wagg edge terms (flagged only).
__global__ void k_scatter(const int* __restrict__ row, const int* __restrict__ col,
                          const unsigned int* __restrict__ needw,
                          const unsigned int* __restrict__ flagbits,
                          const int* __restrict__ count,
                          const int2* __restrict__ pk,
                          int* cursor, int2* srowp, float* wagg, int ne) {
    int e = blockIdx.x * blockDim.x + threadIdx.x;
    if (e < ne) {
        int c = col[e];
        if ((needw[c >> 5] >> (c & 31)) & 1u) {
            int r = row[e];
            int pos = atomicAdd(&cursor[c], 1);
            int2 pr = pk[r];
            srowp[pos] = pr;
            if ((flagbits[c >> 5] >> (c & 31)) & 1u) {    // ~2% of edges
                float dc = __int_as_float(pk[c].y);
                float dr = __int_as_float(pr.y);
                atomicAdd(&wagg[r], (float)count[c] * dc * dr);
            }
        }
    }
}

// -------------------- fused conv1+conv2 over needed nodes (proven body):
//   wsum += wagg[v] * relu( b1 + dv^2*embW1[x[v]] + sum_e d_r*dv*embW1[x_r] )
__global__ void k_fconv(const int* __restrict__ needlist, const int* __restrict__ nneed_p,
                        const float* __restrict__ wagg, const int* __restrict__ x,
                        const int2* __restrict__ srowp,
                        const int* __restrict__ offs, const int* __restrict__ cnt,
                        const float* __restrict__ embW1, const float* __restrict__ b1,
                        float* __restrict__ wsum) {
    int lane = threadIdx.x & 63;
    int wib  = threadIdx.x >> 6;
    int wid  = blockIdx.x * (blockDim.x >> 6) + wib;
    int nw   = gridDim.x * (blockDim.x >> 6);
    int nn   = *nneed_p;
    const float4* __restrict__ ew = (const float4*)embW1;   // row r = ew + r*64
    float4 bfrag = ((const float4*)b1)[lane];
    float4 acc2 = {0.0f, 0.0f, 0.0f, 0.0f};

    for (int i = wid; i < nn; i += nw) {
        int v = needlist[i];
        int cv = cnt[v];
        float dv = rsqrtf((float)cv + 1.0f);
        float wa = wagg[v];
        float4 s = ew[(size_t)x[v] * 64 + lane];
        float w0 = dv * dv;
        float4 acc;
        acc.x = bfrag.x + w0 * s.x;
        acc.y = bfrag.y + w0 * s.y;
        acc.z = bfrag.z + w0 * s.z;
        acc.w = bfrag.w + w0 * s.w;
        int start = offs[v], m = cv;
        for (int base = 0; base < m; base += 64) {
            int mm = min(64, m - base);
            int xr = 0; float wr = 0.0f;
            if (lane < mm) {
                int2 pk2 = srowp[start + base + lane];      // one 8B load
                xr = pk2.x;
                wr = __int_as_float(pk2.y) * dv;
            }
            int e = 0;
            for (; e + 4 <= mm; e += 4) {
                int i0 = __shfl(xr, e),     i1 = __shfl(xr, e + 1);
                int i2 = __shfl(xr, e + 2), i3 = __shfl(xr, e + 3);
                float q0 = __shfl(wr, e),     q1 = __shfl(wr, e + 1);
                float q2 = __shfl(wr, e + 2), q3 = __shfl(wr, e + 3);
                float4 t0 = ew[(size_t)i0 * 64 + lane];
                float4 t1 = ew[(size_t)i1 * 64 + lane];
                float4 t2 = ew[(size_t)i2 * 64 + lane];
                float4 t3 = ew[(size_t)i3 * 64 + lane];
                acc.x += q0 * t0.x + q1 * t1.x + q2 * t2.x + q3 * t3.x;
                acc.y += q0 * t0.y + q1 * t1.y + q2 * t2.y + q3 * t3.y;
                acc.z += q0 * t0.z + q1 * t1.z + q2 * t2.z + q3 * t3.z;
                acc.w += q0 * t0.w + q1 * t1.w + q2 * t2.w + q3 * t3.w;
            }
            for (; e < mm; e++) {
                int i0 = __shfl(xr, e);
                float q0 = __shfl(wr, e);
                float4 t0 = ew[(size_t)i0 * 64 + lane];
                acc.x += q0 * t0.x;
                acc.y += q0 * t0.y;
                acc.z += q0 * t0.z;
                acc.w += q0 * t0.w;
            }
        }
        acc2.x += wa * fmaxf(acc.x, 0.0f);
        acc2.y += wa * fmaxf(acc.y, 0.0f);
        acc2.z += wa * fmaxf(acc.z, 0.0f);
        acc2.w += wa * fmaxf(acc.w, 0.0f);
    }

    __shared__ float red[4][H1D];
    red[wib][4 * lane + 0] = acc2.x;
    red[wib][4 * lane + 1] = acc2.y;
    red[wib][4 * lane + 2] = acc2.z;
    red[wib][4 * lane + 3] = acc2.w;
    __syncthreads();
    int t = threadIdx.x;
    float ssum = red[0][t] + red[1][t] + red[2][t] + red[3][t];
    atomicAdd(&wsum[(blockIdx.x & (NSL - 1)) * H1D + t], ssum);
}

// ---------- k_zout: 64 blocks. Each block: reduce wsum slices, compute
// z = b2 + (ws@W2)/NP (redundant per block, tiny), then 64 output cols with a
// 4-way j-split + LDS reduce.
__global__ void k_zout(const float* __restrict__ wsum, const float* __restrict__ W2,
                       const float* __restrict__ b2, const float* __restrict__ Wc,
                       const float* __restrict__ bc, float* __restrict__ out,
                       float inv_np) {
    __shared__ float ws[H1D];
    __shared__ float z[H2D];
    __shared__ float red[256];
    int t = threadIdx.x;
    float s = 0.0f;
#pragma unroll
    for (int c2 = 0; c2 < NSL; c2++) s += wsum[c2 * H1D + t];
    ws[t] = s;
    __syncthreads();
    if (t < H2D) {
        float acc = 0.0f;
#pragma unroll 8
        for (int k = 0; k < H1D; k++) acc += ws[k] * W2[k * H2D + t];
        z[t] = b2[t] + acc * inv_np;
    }
    __syncthreads();
    int c  = blockIdx.x * 64 + (t & 63);
    int ks = t >> 6;                       // 0..3
    float acc = 0.0f;
#pragma unroll 8
    for (int j = ks * 32; j < ks * 32 + 32; j++) acc += z[j] * Wc[(size_t)j * VOC + c];
    red[t] = acc;
    __syncthreads();
    if (t < 64) {
        int cc = blockIdx.x * 64 + t;
        out[cc] = bc[cc] + red[t] + red[t + 64] + red[t + 128] + red[t + 192];
    }
}

extern "C" void kernel_launch(void* const* d_in, const int* in_sizes, int n_in,
                              void* d_out, int out_size, void* d_ws, size_t ws_size,
                              hipStream_t stream) {
    const int n  = in_sizes[0];
    const int ne = in_sizes[1] / 2;
    const int np = in_sizes[2];

    const int*   x    = (const int*)d_in[0];
    const int*   ei   = (const int*)d_in[1];
    const int*   xpos = (const int*)d_in[2];
    const float* emb  = (const float*)d_in[3];
    const float* W1   = (const float*)d_in[4];
    const float* b1   = (const float*)d_in[5];
    const float* W2   = (const float*)d_in[6];
    const float* b2   = (const float*)d_in[7];
    const float* Wc   = (const float*)d_in[8];
    const float* bc   = (const float*)d_in[9];
    float*       out  = (float*)d_out;

    const int* row = ei;       // edge_index[0]
    const int* col = ei + ne;  // edge_index[1]

    char* p = (char*)d_ws;
    auto alloc = [&](size_t bytes) {
        char* r = p;
        p += (bytes + 255) & ~(size_t)255;
        return r;
    };
    const int nb     = (n + 255) / 256;
    const int neb    = (ne + 255) / 256;
    const int nwords = nb * 8;   // (nb*256)/32 — padded so ballot stores stay in-bounds
    const int R      = (n + NRANGE - 1) / NRANGE;   // nodes per histogram range
    const int sTeam  = NRANGE * R;                  // per-team partial stride

    int*          cnt      = (int*)alloc((size_t)n * 4);
    int*          offs     = (int*)alloc((size_t)n * 4);
    int*          cursor   = (int*)alloc((size_t)n * 4);
    int*          count    = (int*)alloc((size_t)n * 4);
    int*          needlist = (int*)alloc((size_t)n * 4);
    unsigned int* needw    = (unsigned int*)alloc((size_t)nwords * 4);
    unsigned int* flagbits = (unsigned int*)alloc((size_t)nwords * 4);
    int2*         srowp    = (int2*)alloc((size_t)ne * 8);
    int2*         pk       = (int2*)alloc((size_t)n * 8);
    int*          cntp     = (int*)alloc((size_t)TEAMS * sTeam * 4);
    int*          nflag    = (int*)alloc(256 * 4);
    int*          total    = (int*)alloc(256 * 4);
    float*        wagg     = (float*)alloc((size_t)n * 4);
    float*        embW1    = (float*)alloc((size_t)VOC * H1D * 4);
    float*        wsum     = (float*)alloc((size_t)NSL * H1D * 4);

    kA_init<<<nb, 256, 0, stream>>>(count, flagbits, needw, wagg, wsum,
                                    nflag, total, xpos, n, nwords, np);
    kB_embW1_hist<<<KB_GRID, 256, 0, stream>>>(emb, W1, embW1, row, col, flagbits,
                                               cntp, needw, ne, R);
    k_alloc<<<nb, 256, 0, stream>>>(needw, flagbits, cntp, count, x, wagg,
                                    needlist, nflag, total, offs, cursor, pk, cnt,
                                    n, sTeam);
    k_scatter<<<neb, 256, 0, stream>>>(row, col, needw, flagbits, count, pk,
                                       cursor, srowp, wagg, ne);
    k_fconv<<<2048, 256, 0, stream>>>(needlist, nflag, wagg, x, srowp, offs, cnt,
                                      embW1, b1, wsum);
    k_zout<<<VOC / 64, 256, 0, stream>>>(wsum, W2, b2, Wc, bc, out, 1.0f / (float)np);
}

// Round 5
// 169.708 us; speedup vs baseline: 2.2555x; 2.2555x over previous
//
#include <hip/hip_runtime.h>

constexpr int EMB  = 128;   // EMB_DIM
constexpr int H1D  = 256;   // 2*HIDDEN
constexpr int H2D  = 128;   // HIDDEN
constexpr int VOC  = 4096;  // VOCAB
constexpr int NSL  = 32;    // wsum slices (atomic-contention spreading)
constexpr int RPB  = 4;     // emb rows per tile in embW1 GEMM

// LDS-privatized histogram: 8 node-ranges x 128 edge-slice teams = 1024 blocks.
// Per block: 6250-edge sweep (24 iters/thread), 25.6KB u32 LDS counts
// (6 blocks/CU co-resident -> latency hidden; R4's 1-block/CU serialization fixed).
// Partials stored as u16 (max per-slice count 6400 < 65536). n <= NRANGE*RCAP.
constexpr int NRANGE = 8;
constexpr int TEAMS  = 128;
constexpr int RCAP   = 6400;                  // lc[] capacity (25.6 KB)
constexpr int HIST_B = NRANGE * TEAMS;        // 1024 (first in grid: critical path)
constexpr int GEMM_B = VOC / RPB;             // 1024
constexpr int KB_GRID = HIST_B + GEMM_B;      // 2048

// ---------------- kA: zero state; block 0 builds flagbits + count from x_position.
// cnt[] is NOT zeroed: k_alloc fully writes it (sum of partials) before any reader.
__global__ void kA_init(int* count, unsigned int* flagbits, unsigned int* needw,
                        float* wagg, float* wsum, int* nflag, int* total,
                        const int* __restrict__ xpos,
                        int n, int nwords, int np) {
    int t = threadIdx.x;
    if (blockIdx.x == 0) {
        for (int i = t; i < nwords; i += 256) flagbits[i] = 0u;
        for (int i = t; i < n; i += 256) count[i] = 0;
        __syncthreads();
        for (int i = t; i < np; i += 256) {
            int v = xpos[i];
            atomicAdd(&count[v], 1);
            atomicOr(&flagbits[v >> 5], 1u << (v & 31));
        }
        if (t == 0) { *nflag = 0; *total = 0; }
    } else {
        const int stride = (gridDim.x - 1) * 256;
        const int i0 = (blockIdx.x - 1) * 256 + t;
        for (int i = i0; i < n; i += stride) wagg[i] = 0.0f;
        for (int i = i0; i < nwords; i += stride) needw[i] = 0u;
        for (int i = i0; i < NSL * H1D; i += stride) wsum[i] = 0.0f;
    }
}

// ---------------- kB: blocks [0,1024): LDS-privatized histogram + needed-row marks
//                  || blocks [1024,2048): embW1 = emb @ W1 (one 4-row tile each).
// Hist block h: team = h/8 (owns a 6250-edge slice), range = h&7 (owns nodes
// [range*R, range*R+R)). Counts in LDS (no global atomics), written out as plain
// coalesced u16 stores. Flag-test + mark runs in the unique owning range block.
__global__ __launch_bounds__(256) void kB_embW1_hist(
        const float* __restrict__ emb, const float* __restrict__ W1,
        float* __restrict__ embW1,
        const int* __restrict__ row, const int* __restrict__ col,
        const unsigned int* __restrict__ flagbits,
        unsigned short* __restrict__ cntp16, unsigned int* markw,
        int ne, int R, int sTeam) {
    __shared__ int sbuf[RCAP];           // 25.6 KB (GEMM path reuses first 2 KB)
    int t = threadIdx.x;
    if (blockIdx.x < HIST_B) {
        int h     = blockIdx.x;
        int team  = h >> 3;              // / NRANGE
        int range = h & (NRANGE - 1);
        int base  = range * R;
        for (int i = t; i < R; i += 256) sbuf[i] = 0;
        __syncthreads();
        int q  = (((ne + TEAMS - 1) / TEAMS) + 255) & ~255;   // 256-aligned slice
        int e0 = team * q;
        int e1 = min(ne, e0 + q);
        for (int e = e0 + t; e < e1; e += 256) {
            int c = col[e];
            unsigned int d = (unsigned int)(c - base);
            if (d < (unsigned int)R) {
                atomicAdd(&sbuf[d], 1);                        // LDS atomic
                if ((flagbits[c >> 5] >> (c & 31)) & 1u) {     // ~2% of edges
                    int r = row[e];
                    atomicOr(&markw[r >> 5], 1u << (r & 31));
                }
            }
        }
        __syncthreads();
        unsigned short* outp = cntp16 + (size_t)team * sTeam + base;
        for (int i = t; i < R; i += 256) outp[i] = (unsigned short)sbuf[i];
    } else {
        float (*er)[EMB] = (float (*)[EMB])sbuf;   // 2 KB of sbuf
        int r0 = (blockIdx.x - HIST_B) * RPB;
        for (int i = t; i < RPB * EMB; i += 256)
            er[i / EMB][i % EMB] = emb[(size_t)r0 * EMB + i];
        __syncthreads();
        float acc[RPB];
#pragma unroll
        for (int rr = 0; rr < RPB; rr++) acc[rr] = 0.0f;
        for (int k = 0; k < EMB; k++) {
            float w = W1[k * H1D + t];
#pragma unroll
            for (int rr = 0; rr < RPB; rr++) acc[rr] += er[rr][k] * w;
        }
#pragma unroll
        for (int rr = 0; rr < RPB; rr++)
            embW1[(size_t)(r0 + rr) * H1D + t] = acc[rr];
    }
}

// ------- k_alloc: cv = sum of 128 u16 histogram partials (written to cnt[]);
//         need = mark||flag; canonical needbits via wave-ballot plain store;
//         CSR bump-alloc (wave-aggregated atomics); wagg self term;
//         packed pk[v] = {x[v], rsqrt(cnt[v]+1)} so scatter does 1 gather not 2.
__global__ void k_alloc(unsigned int* needw,
                        const unsigned int* __restrict__ flagbits,
                        const unsigned short* __restrict__ cntp16,
                        const int* __restrict__ count,
                        const int* __restrict__ x,
                        float* wagg, int* needlist, int* nflag, int* total,
                        int* offs, int* cursor, int2* pk, int* cnt,
                        int n, int sTeam) {
    int v = blockIdx.x * blockDim.x + threadIdx.x;
    int lane = threadIdx.x & 63;
    int cv = 0;
    bool need = false;
    if (v < n) {
        const unsigned short* cp = cntp16 + v;
#pragma unroll 8
        for (int tt = 0; tt < TEAMS; tt++) cv += cp[(size_t)tt * sTeam];
        cnt[v] = cv;
        float dv = rsqrtf((float)cv + 1.0f);
        int2 p; p.x = x[v]; p.y = __float_as_int(dv);
        pk[v] = p;
        bool mark = (needw[v >> 5] >> (v & 31)) & 1u;
        bool flag = (flagbits[v >> 5] >> (v & 31)) & 1u;
        need = mark || flag;
        if (flag) wagg[v] = (float)count[v] / ((float)cv + 1.0f);  // count*dinv^2
    }
    // canonical needbits: ballot -> one word per half-wave, plain store by owner lane
    unsigned long long nm = __ballot(need);
    int wbase = (v & ~63) >> 5;            // v is wave-aligned at lane 0
    if (lane == 0)  needw[wbase]     = (unsigned int)(nm & 0xffffffffu);
    if (lane == 32) needw[wbase + 1] = (unsigned int)(nm >> 32);
    int seg = need ? cv : 0;
    int incl = seg;
#pragma unroll
    for (int d = 1; d < 64; d <<= 1) {
        int t2 = __shfl_up(incl, d);
        if (lane >= d) incl += t2;
    }
    int excl = incl - seg;
    int wave_total = __shfl(incl, 63);
    int rank = __popcll(nm & ((1ull << lane) - 1));
    int wcnt = __popcll(nm);
    int base_id = 0, base_off = 0;
    if (lane == 0) {
        if (wcnt > 0)       base_id  = atomicAdd(nflag, wcnt);
        if (wave_total > 0) base_off = atomicAdd(total, wave_total);
    }
    base_id  = __shfl(base_id, 0);
    base_off = __shfl(base_off, 0);
    if (need) {
        needlist[base_id + rank] = v;
        int o = base_off + excl;
        offs[v] = o;
        cursor[v] = o;
    }
}

// ---------------- k_scatter: filtered to needed cols via L1-resident bitmask;
//   srowp[pos] = pk[row] (single 8B gather); wagg edge terms (flagged only).
__global__ void k_scatter(const int* __restrict__ row, const int* __restrict__ col,
                          const unsigned int* __restrict__ needw,
                          const unsigned int* __restrict__ flagbits,
                          const int* __restrict__ count,
                          const int2* __restrict__ pk,
                          int* cursor, int2* srowp, float* wagg, int ne) {
    int e = blockIdx.x * blockDim.x + threadIdx.x;
    if (e < ne) {
        int c = col[e];
        if ((needw[c >> 5] >> (c & 31)) & 1u) {
            int r = row[e];
            int pos = atomicAdd(&cursor[c], 1);
            int2 pr = pk[r];
            srowp[pos] = pr;
            if ((flagbits[c >> 5] >> (c & 31)) & 1u) {    // ~2% of edges
                float dc = __int_as_float(pk[c].y);
                float dr = __int_as_float(pr.y);
                atomicAdd(&wagg[r], (float)count[c] * dc * dr);
            }
        }
    }
}

// -------------------- fused conv1+conv2 over needed nodes (proven body):
//   wsum += wagg[v] * relu( b1 + dv^2*embW1[x[v]] + sum_e d_r*dv*embW1[x_r] )
__global__ void k_fconv(const int* __restrict__ needlist, const int* __restrict__ nneed_p,
                        const float* __restrict__ wagg, const int* __restrict__ x,
                        const int2* __restrict__ srowp,
                        const int* __restrict__ offs, const int* __restrict__ cnt,
                        const float* __restrict__ embW1, const float* __restrict__ b1,
                        float* __restrict__ wsum) {
    int lane = threadIdx.x & 63;
    int wib  = threadIdx.x >> 6;
    int wid  = blockIdx.x * (blockDim.x >> 6) + wib;
    int nw   = gridDim.x * (blockDim.x >> 6);
    int nn   = *nneed_p;
    const float4* __restrict__ ew = (const float4*)embW1;   // row r = ew + r*64
    float4 bfrag = ((const float4*)b1)[lane];
    float4 acc2 = {0.0f, 0.0f, 0.0f, 0.0f};

    for (int i = wid; i < nn; i += nw) {
        int v = needlist[i];
        int cv = cnt[v];
        float dv = rsqrtf((float)cv + 1.0f);
        float wa = wagg[v];
        float4 s = ew[(size_t)x[v] * 64 + lane];
        float w0 = dv * dv;
        float4 acc;
        acc.x = bfrag.x + w0 * s.x;
        acc.y = bfrag.y + w0 * s.y;
        acc.z = bfrag.z + w0 * s.z;
        acc.w = bfrag.w + w0 * s.w;
        int start = offs[v], m = cv;
        for (int base = 0; base < m; base += 64) {
            int mm = min(64, m - base);
            int xr = 0; float wr = 0.0f;
            if (lane < mm) {
                int2 pk2 = srowp[start + base + lane];      // one 8B load
                xr = pk2.x;
                wr = __int_as_float(pk2.y) * dv;
            }
            int e = 0;
            for (; e + 4 <= mm; e += 4) {
                int i0 = __shfl(xr, e),     i1 = __shfl(xr, e + 1);
                int i2 = __shfl(xr, e + 2), i3 = __shfl(xr, e + 3);
                float q0 = __shfl(wr, e),     q1 = __shfl(wr, e + 1);
                float q2 = __shfl(wr, e + 2), q3 = __shfl(wr, e + 3);
                float4 t0 = ew[(size_t)i0 * 64 + lane];
                float4 t1 = ew[(size_t)i1 * 64 + lane];
                float4 t2 = ew[(size_t)i2 * 64 + lane];
                float4 t3 = ew[(size_t)i3 * 64 + lane];
                acc.x += q0 * t0.x + q1 * t1.x + q2 * t2.x + q3 * t3.x;
                acc.y += q0 * t0.y + q1 * t1.y + q2 * t2.y + q3 * t3.y;
                acc.z += q0 * t0.z + q1 * t1.z + q2 * t2.z + q3 * t3.z;
                acc.w += q0 * t0.w + q1 * t1.w + q2 * t2.w + q3 * t3.w;
            }
            for (; e < mm; e++) {
                int i0 = __shfl(xr, e);
                float q0 = __shfl(wr, e);
                float4 t0 = ew[(size_t)i0 * 64 + lane];
                acc.x += q0 * t0.x;
                acc.y += q0 * t0.y;
                acc.z += q0 * t0.z;
                acc.w += q0 * t0.w;
            }
        }
        acc2.x += wa * fmaxf(acc.x, 0.0f);
        acc2.y += wa * fmaxf(acc.y, 0.0f);
        acc2.z += wa * fmaxf(acc.z, 0.0f);
        acc2.w += wa * fmaxf(acc.w, 0.0f);
    }

    __shared__ float red[4][H1D];
    red[wib][4 * lane + 0] = acc2.x;
    red[wib][4 * lane + 1] = acc2.y;
    red[wib][4 * lane + 2] = acc2.z;
    red[wib][4 * lane + 3] = acc2.w;
    __syncthreads();
    int t = threadIdx.x;
    float ssum = red[0][t] + red[1][t] + red[2][t] + red[3][t];
    atomicAdd(&wsum[(blockIdx.x & (NSL - 1)) * H1D + t], ssum);
}

// ---------- k_zout: 64 blocks. Each block: reduce wsum slices, compute
// z = b2 + (ws@W2)/NP (redundant per block, tiny), then 64 output cols with a
// 4-way j-split + LDS reduce.
__global__ void k_zout(const float* __restrict__ wsum, const float* __restrict__ W2,
                       const float* __restrict__ b2, const float* __restrict__ Wc,
                       const float* __restrict__ bc, float* __restrict__ out,
                       float inv_np) {
    __shared__ float ws[H1D];
    __shared__ float z[H2D];
    __shared__ float red[256];
    int t = threadIdx.x;
    float s = 0.0f;
#pragma unroll
    for (int c2 = 0; c2 < NSL; c2++) s += wsum[c2 * H1D + t];
    ws[t] = s;
    __syncthreads();
    if (t < H2D) {
        float acc = 0.0f;
#pragma unroll 8
        for (int k = 0; k < H1D; k++) acc += ws[k] * W2[k * H2D + t];
        z[t] = b2[t] + acc * inv_np;
    }
    __syncthreads();
    int c  = blockIdx.x * 64 + (t & 63);
    int ks = t >> 6;                       // 0..3
    float acc = 0.0f;
#pragma unroll 8
    for (int j = ks * 32; j < ks * 32 + 32; j++) acc += z[j] * Wc[(size_t)j * VOC + c];
    red[t] = acc;
    __syncthreads();
    if (t < 64) {
        int cc = blockIdx.x * 64 + t;
        out[cc] = bc[cc] + red[t] + red[t + 64] + red[t + 128] + red[t + 192];
    }
}

extern "C" void kernel_launch(void* const* d_in, const int* in_sizes, int n_in,
                              void* d_out, int out_size, void* d_ws, size_t ws_size,
                              hipStream_t stream) {
    const int n  = in_sizes[0];
    const int ne = in_sizes[1] / 2;
    const int np = in_sizes[2];

    const int*   x    = (const int*)d_in[0];
    const int*   ei   = (const int*)d_in[1];
    const int*   xpos = (const int*)d_in[2];
    const float* emb  = (const float*)d_in[3];
    const float* W1   = (const float*)d_in[4];
    const float* b1   = (const float*)d_in[5];
    const float* W2   = (const float*)d_in[6];
    const float* b2   = (const float*)d_in[7];
    const float* Wc   = (const float*)d_in[8];
    const float* bc   = (const float*)d_in[9];
    float*       out  = (float*)d_out;

    const int* row = ei;       // edge_index[0]
    const int* col = ei + ne;  // edge_index[1]

    char* p = (char*)d_ws;
    auto alloc = [&](size_t bytes) {
        char* r = p;
        p += (bytes + 255) & ~(size_t)255;
        return r;
    };
    const int nb     = (n + 255) / 256;
    const int neb    = (ne + 255) / 256;
    const int nwords = nb * 8;   // (nb*256)/32 — padded so ballot stores stay in-bounds
    const int R      = (n + NRANGE - 1) / NRANGE;   // nodes per histogram range (<=RCAP)
    const int sTeam  = NRANGE * R;                  // per-team partial stride (>= n)

    int*            cnt      = (int*)alloc((size_t)n * 4);
    int*            offs     = (int*)alloc((size_t)n * 4);
    int*            cursor   = (int*)alloc((size_t)n * 4);
    int*            count    = (int*)alloc((size_t)n * 4);
    int*            needlist = (int*)alloc((size_t)n * 4);
    unsigned int*   needw    = (unsigned int*)alloc((size_t)nwords * 4);
    unsigned int*   flagbits = (unsigned int*)alloc((size_t)nwords * 4);
    int2*           srowp    = (int2*)alloc((size_t)ne * 8);
    int2*           pk       = (int2*)alloc((size_t)n * 8);
    unsigned short* cntp16   = (unsigned short*)alloc((size_t)TEAMS * sTeam * 2);
    int*            nflag    = (int*)alloc(256 * 4);
    int*            total    = (int*)alloc(256 * 4);
    float*          wagg     = (float*)alloc((size_t)n * 4);
    float*          embW1    = (float*)alloc((size_t)VOC * H1D * 4);
    float*          wsum     = (float*)alloc((size_t)NSL * H1D * 4);

    kA_init<<<nb, 256, 0, stream>>>(count, flagbits, needw, wagg, wsum,
                                    nflag, total, xpos, n, nwords, np);
    kB_embW1_hist<<<KB_GRID, 256, 0, stream>>>(emb, W1, embW1, row, col, flagbits,
                                               cntp16, needw, ne, R, sTeam);
    k_alloc<<<nb, 256, 0, stream>>>(needw, flagbits, cntp16, count, x, wagg,
                                    needlist, nflag, total, offs, cursor, pk, cnt,
                                    n, sTeam);
    k_scatter<<<neb, 256, 0, stream>>>(row, col, needw, flagbits, count, pk,
                                       cursor, srowp, wagg, ne);
    k_fconv<<<2048, 256, 0, stream>>>(needlist, nflag, wagg, x, srowp, offs, cnt,
                                      embW1, b1, wsum);
    k_zout<<<VOC / 64, 256, 0, stream>>>(wsum, W2, b2, Wc, bc, out, 1.0f / (float)np);
}